// Round 1
// baseline (1887.830 us; speedup 1.0000x reference)
//
#include <hip/hip_runtime.h>
#include <hip/hip_bf16.h>

typedef _Float16 f16;
typedef __attribute__((ext_vector_type(8))) _Float16 f16x8;
typedef __attribute__((ext_vector_type(4))) float f32x4;

// Problem constants
constexpr int CB = 64;     // batch
constexpr int CP = 196;    // pixels
constexpr int CH = 512;    // hidden / encoder dim
constexpr int CV = 30000;  // vocab
constexpr int CVP = 30080; // vocab padded to 128
constexpr int CT = 20;     // steps
constexpr int CK = 512;    // all GEMMs have K=512

__device__ __forceinline__ float sigf(float x) { return 1.f / (1.f + __expf(-x)); }

// ---------------------------------------------------------------------------
// Generic K=512 GEMM:  C[M,N] = A[M,512] @ B[N,512]^T (+bias, epilogue variants)
// A: f16 (or f32 converted on the fly), B: f16. 256 threads, 4 waves in 2x2.
// Tile: BM x 128, BK=32. mfma_f32_16x16x32_f16.
// ---------------------------------------------------------------------------
enum { EPI_F16B = 0, EPI_F32B = 1, EPI_PREDS = 2 };

template <int BM, int EPI, bool AF32>
__global__ __launch_bounds__(256) void gemm_k512(
    const void* __restrict__ Aptr, const f16* __restrict__ Bptr, int N,
    const float* __restrict__ bias, float* __restrict__ Cf,
    f16* __restrict__ Ch, const int* __restrict__ lengths)
{
    constexpr int MI = BM / 32;   // M-fragments per wave (128->4, 64->2)
    constexpr int ALD = BM / 64;  // 16B A-chunks per thread (128->2, 64->1)
    const int tid = threadIdx.x;
    const int lane = tid & 63, wave = tid >> 6;
    const int wr = wave >> 1, wc = wave & 1;

    __shared__ f16 As[BM * 32];
    __shared__ f16 Bs[128 * 32];

    const size_t arowbase = (size_t)blockIdx.y * BM;
    const f16* Bg = Bptr + (size_t)blockIdx.x * 128 * CK;

    f32x4 acc[MI][4] = {};

    for (int k0 = 0; k0 < CK; k0 += 32) {
        f16x8 ar[ALD], br[2];
#pragma unroll
        for (int i = 0; i < ALD; ++i) {
            int off = (tid + i * 256) * 8;  // halves into A tile
            int row = off >> 5;
            int kc = off & 31;
            if constexpr (AF32) {
                const float* Af = (const float*)Aptr + (arowbase + row) * CK + k0 + kc;
#pragma unroll
                for (int j = 0; j < 8; ++j) ar[i][j] = (f16)Af[j];
            } else {
                const f16* Ah = (const f16*)Aptr + (arowbase + row) * CK + k0 + kc;
                ar[i] = *(const f16x8*)Ah;
            }
        }
#pragma unroll
        for (int i = 0; i < 2; ++i) {
            int off = (tid + i * 256) * 8;
            int row = off >> 5;
            int kc = off & 31;
            br[i] = *(const f16x8*)&Bg[(size_t)row * CK + k0 + kc];
        }
        __syncthreads();  // previous iteration's LDS reads done
#pragma unroll
        for (int i = 0; i < ALD; ++i) *(f16x8*)&As[(tid + i * 256) * 8] = ar[i];
#pragma unroll
        for (int i = 0; i < 2; ++i) *(f16x8*)&Bs[(tid + i * 256) * 8] = br[i];
        __syncthreads();

        const int kg = (lane >> 4) * 8;
        const int rr = lane & 15;
        f16x8 af[MI], bf[4];
#pragma unroll
        for (int mi = 0; mi < MI; ++mi)
            af[mi] = *(const f16x8*)&As[(wr * (BM / 2) + mi * 16 + rr) * 32 + kg];
#pragma unroll
        for (int ni = 0; ni < 4; ++ni)
            bf[ni] = *(const f16x8*)&Bs[(wc * 64 + ni * 16 + rr) * 32 + kg];
#pragma unroll
        for (int mi = 0; mi < MI; ++mi)
#pragma unroll
            for (int ni = 0; ni < 4; ++ni)
                acc[mi][ni] = __builtin_amdgcn_mfma_f32_16x16x32_f16(
                    af[mi], bf[ni], acc[mi][ni], 0, 0, 0);
    }

    const int m0 = blockIdx.y * BM + wr * (BM / 2);
    const int n0 = blockIdx.x * 128 + wc * 64;
    const int r0 = (lane >> 4) * 4;  // C/D: row=(lane>>4)*4+reg, col=lane&15
    const int cc = lane & 15;
#pragma unroll
    for (int mi = 0; mi < MI; ++mi) {
#pragma unroll
        for (int ni = 0; ni < 4; ++ni) {
#pragma unroll
            for (int r = 0; r < 4; ++r) {
                int m = m0 + mi * 16 + r0 + r;
                int n = n0 + ni * 16 + cc;
                float v = acc[mi][ni][r];
                if constexpr (EPI == EPI_F16B) {
                    Ch[(size_t)m * N + n] = (f16)(v + bias[n]);
                } else if constexpr (EPI == EPI_F32B) {
                    if (bias) v += bias[n];
                    Cf[(size_t)m * N + n] = v;
                } else {  // EPI_PREDS: m = t*64+b; scatter to out[b][t][n], mask
                    if (n < CV) {
                        int tt = m >> 6, b = m & 63;
                        float val = ((lengths[b] - 1) > tt) ? (v + bias[n]) : 0.f;
                        Cf[(size_t)b * (CT * CV) + (size_t)tt * CV + n] = val;
                    }
                }
            }
        }
    }
}

// ---------------------------------------------------------------------------
// fp32 -> fp16 convert with source pitch (for W_ih column slices)
// ---------------------------------------------------------------------------
__global__ void k_cvt(const float* __restrict__ src, f16* __restrict__ dst,
                      long long total, int cols, int spitch)
{
    long long i = (long long)blockIdx.x * blockDim.x + threadIdx.x;
    long long stride = (long long)gridDim.x * blockDim.x;
    for (; i < total; i += stride) {
        long long r = i / cols;
        int c = (int)(i - r * cols);
        dst[i] = (f16)src[r * spitch + c];
    }
}

// gather emb rows for all (t,b): row m = t*64+b  <- emb[captions[b*21+t]]
__global__ void k_gather(const float* __restrict__ emb, const int* __restrict__ caps,
                         f16* __restrict__ dst)
{
    int i = blockIdx.x * 256 + threadIdx.x;  // total 1280*512
    int e = i & 511;
    int m = i >> 9;
    int tt = m >> 6, b = m & 63;
    dst[i] = (f16)emb[(size_t)caps[b * 21 + tt] * CH + e];
}

// bcat = [b_da; b_fb; 0(2048)],  bsum = b_ih + b_hh
__global__ void k_prep(const float* b_da, const float* b_fb, const float* b_ih,
                       const float* b_hh, float* bcat, float* bsum)
{
    int i = blockIdx.x * 256 + threadIdx.x;
    if (i < 3072) bcat[i] = (i < 512) ? b_da[i] : (i < 1024 ? b_fb[i - 512] : 0.f);
    if (i < 2048) bsum[i] = b_ih[i] + b_hh[i];
}

// h0 = mean_p(enc), c0 = h0
__global__ __launch_bounds__(256) void k_h0(const float* __restrict__ enc,
                                            f16* __restrict__ h0h, float* __restrict__ c0)
{
    int b = blockIdx.x;
    for (int h = threadIdx.x; h < CH; h += 256) {
        const float* p = enc + (size_t)b * CP * CH + h;
        float s = 0.f;
        for (int q = 0; q < CP; ++q) s += p[q * CH];
        s *= (1.f / 196.f);
        h0h[b * CH + h] = (f16)s;
        c0[b * CH + h] = s;
    }
}

// Attention for one step: per-b block.
// e = relu(att1[b]+att2[b])@W_fa + b_fa; alpha = softmax(e); awe = alpha@enc[b];
// xawe = sigmoid(gatearg)*awe (f16). Also writes masked alpha to output.
__global__ __launch_bounds__(256) void k_attn(
    const f16* __restrict__ att1, const float* __restrict__ enc,
    const float* __restrict__ Y, const float* __restrict__ W_fa,
    const float* __restrict__ b_fa, float* __restrict__ alph_out,
    const int* __restrict__ lengths, f16* __restrict__ xawe, int t)
{
    int b = blockIdx.x;
    int tid = threadIdx.x;
    int lane = tid & 63, wv = tid >> 6;

    __shared__ float att2s[CH], wfas[CH], es[CP], als[CP], red[8];

    for (int i = tid; i < CH; i += 256) {
        att2s[i] = Y[b * 3072 + i];
        wfas[i] = W_fa[i];
    }
    __syncthreads();

    for (int p = wv; p < CP; p += 4) {
        const f16* ap = att1 + (size_t)(b * CP + p) * CH;
        float s = 0.f;
#pragma unroll
        for (int j = 0; j < 8; ++j) {
            int a = lane + 64 * j;
            float v = (float)ap[a] + att2s[a];
            s += fmaxf(v, 0.f) * wfas[a];
        }
#pragma unroll
        for (int o = 32; o; o >>= 1) s += __shfl_down(s, o);
        if (lane == 0) es[p] = s + b_fa[0];
    }
    __syncthreads();

    float ev = (tid < CP) ? es[tid] : -1e30f;
    float mx = ev;
#pragma unroll
    for (int o = 32; o; o >>= 1) mx = fmaxf(mx, __shfl_down(mx, o));
    if (lane == 0) red[wv] = mx;
    __syncthreads();
    mx = fmaxf(fmaxf(red[0], red[1]), fmaxf(red[2], red[3]));
    float ex = (tid < CP) ? __expf(ev - mx) : 0.f;
    float sm = ex;
#pragma unroll
    for (int o = 32; o; o >>= 1) sm += __shfl_down(sm, o);
    if (lane == 0) red[4 + wv] = sm;
    __syncthreads();
    sm = red[4] + red[5] + red[6] + red[7];
    float alpha = ex / sm;
    if (tid < CP) {
        als[tid] = alpha;
        bool act = (lengths[b] - 1) > t;
        alph_out[(size_t)b * (CT * CP) + t * CP + tid] = act ? alpha : 0.f;
    }
    __syncthreads();

    for (int h = tid; h < CH; h += 256) {
        const float* ep = enc + (size_t)b * CP * CH + h;
        float s = 0.f;
#pragma unroll 4
        for (int p = 0; p < CP; ++p) s += als[p] * ep[p * CH];
        float gate = sigf(Y[b * 3072 + 512 + h]);
        xawe[b * CH + h] = (f16)(gate * s);
    }
}

// LSTM cell pointwise: gates = g2 + embIH_t + Y[:,1024:3072]; update c; h->f16
__global__ __launch_bounds__(256) void k_cell(
    const float* __restrict__ g2, const float* __restrict__ embIH_t,
    const float* __restrict__ Y, float* __restrict__ cbuf, f16* __restrict__ hbuf_t)
{
    int i = blockIdx.x * 256 + threadIdx.x;  // 64*512
    int b = i >> 9, n = i & 511;
    const float* gg2 = g2 + (size_t)b * 2048;
    const float* ei = embIH_t + (size_t)b * 2048;
    const float* yh = Y + (size_t)b * 3072 + 1024;
    float gi = gg2[n] + ei[n] + yh[n];
    float gf = gg2[n + 512] + ei[n + 512] + yh[n + 512];
    float gg = gg2[n + 1024] + ei[n + 1024] + yh[n + 1024];
    float go = gg2[n + 1536] + ei[n + 1536] + yh[n + 1536];
    float c = sigf(gf) * cbuf[i] + sigf(gi) * tanhf(gg);
    cbuf[i] = c;
    hbuf_t[i] = (f16)(sigf(go) * tanhf(c));
}

// ---------------------------------------------------------------------------
extern "C" void kernel_launch(void* const* d_in, const int* in_sizes, int n_in,
                              void* d_out, int out_size, void* d_ws, size_t ws_size,
                              hipStream_t stream)
{
    const float* enc  = (const float*)d_in[0];
    const int*   caps = (const int*)d_in[1];
    const int*   lens = (const int*)d_in[2];
    const float* emb  = (const float*)d_in[3];
    const float* W_ea = (const float*)d_in[4];
    const float* b_ea = (const float*)d_in[5];
    const float* b_da = (const float*)d_in[7];
    const float* W_fa = (const float*)d_in[8];
    const float* b_fa = (const float*)d_in[9];
    const float* b_fb = (const float*)d_in[11];
    const float* W_ih = (const float*)d_in[12];
    const float* W_hh = (const float*)d_in[13];
    const float* b_ih = (const float*)d_in[14];
    const float* b_hh = (const float*)d_in[15];
    const float* W_fc = (const float*)d_in[16];
    const float* b_fc = (const float*)d_in[17];
    const float* W_da = (const float*)d_in[6];
    const float* W_fb = (const float*)d_in[10];

    float* out = (float*)d_out;
    float* alph_out = out + (size_t)CB * CT * CV;

    char* p = (char*)d_ws;
    auto carve = [&](size_t bytes) {
        char* r = p;
        p += (bytes + 255) & ~(size_t)255;
        return r;
    };
    f16* Wea_h   = (f16*)carve((size_t)512 * 512 * 2);
    f16* att1_h  = (f16*)carve((size_t)CB * CP * CH * 2);     // 12.85 MB
    f16* embg_h  = (f16*)carve((size_t)1280 * 512 * 2);
    f16* WihE_h  = (f16*)carve((size_t)2048 * 512 * 2);
    f16* WihA_h  = (f16*)carve((size_t)2048 * 512 * 2);
    f16* Wcat_h  = (f16*)carve((size_t)3072 * 512 * 2);
    f16* Wfc_h   = (f16*)carve((size_t)CVP * 512 * 2);        // 30.8 MB
    float* embIH = (float*)carve((size_t)1280 * 2048 * 4);    // 10.5 MB
    float* bsum  = (float*)carve(2048 * 4);
    float* bcat  = (float*)carve(3072 * 4);
    f16* h0_h    = (f16*)carve((size_t)64 * 512 * 2);
    f16* hbuf_h  = (f16*)carve((size_t)1280 * 512 * 2);
    float* cbuf  = (float*)carve((size_t)64 * 512 * 4);
    float* Ybuf  = (float*)carve((size_t)64 * 3072 * 4);
    f16* xawe_h  = (f16*)carve((size_t)64 * 512 * 2);
    float* g2buf = (float*)carve((size_t)64 * 2048 * 4);

    auto cvt = [&](const float* s, f16* d, long long rows, int cols, int spitch) {
        long long total = rows * cols;
        long long g = (total + 255) / 256;
        int grid = (int)(g < 8192 ? g : 8192);
        hipLaunchKernelGGL(k_cvt, dim3(grid), dim3(256), 0, stream, s, d, total, cols, spitch);
    };
    cvt(W_ea, Wea_h, 512, 512, 512);
    cvt(W_da, Wcat_h, 512, 512, 512);
    cvt(W_fb, Wcat_h + 512 * 512, 512, 512, 512);
    cvt(W_hh, Wcat_h + 1024 * 512, 2048, 512, 512);
    cvt(W_ih, WihE_h, 2048, 512, 1024);         // cols 0..511 of W_ih
    cvt(W_ih + 512, WihA_h, 2048, 512, 1024);   // cols 512..1023
    cvt(W_fc, Wfc_h, CV, 512, 512);
    (void)hipMemsetAsync(Wfc_h + (size_t)CV * 512, 0, (size_t)(CVP - CV) * 512 * 2, stream);

    hipLaunchKernelGGL(k_gather, dim3(2560), dim3(256), 0, stream, emb, caps, embg_h);
    hipLaunchKernelGGL(k_prep, dim3(12), dim3(256), 0, stream, b_da, b_fb, b_ih, b_hh, bcat, bsum);
    hipLaunchKernelGGL(k_h0, dim3(64), dim3(256), 0, stream, enc, h0_h, cbuf);

    // att1 = enc @ W_ea^T + b_ea   (M=12544, N=512) -> f16
    hipLaunchKernelGGL((gemm_k512<128, EPI_F16B, true>), dim3(4, 98), dim3(256), 0, stream,
                       (const void*)enc, Wea_h, 512, b_ea, (float*)nullptr, att1_h, (const int*)nullptr);
    // embIH = emb_seq @ W_ihE^T + (b_ih+b_hh)   (M=1280, N=2048) -> f32
    hipLaunchKernelGGL((gemm_k512<128, EPI_F32B, false>), dim3(16, 10), dim3(256), 0, stream,
                       (const void*)embg_h, WihE_h, 2048, bsum, embIH, (f16*)nullptr, (const int*)nullptr);

    for (int t = 0; t < CT; ++t) {
        const f16* hprev = (t == 0) ? h0_h : (hbuf_h + (size_t)(t - 1) * 64 * 512);
        // Y = h @ [W_da; W_fb; W_hh]^T + [b_da; b_fb; 0]   (M=64, N=3072)
        hipLaunchKernelGGL((gemm_k512<64, EPI_F32B, false>), dim3(24, 1), dim3(256), 0, stream,
                           (const void*)hprev, Wcat_h, 3072, bcat, Ybuf, (f16*)nullptr, (const int*)nullptr);
        hipLaunchKernelGGL(k_attn, dim3(64), dim3(256), 0, stream,
                           att1_h, enc, Ybuf, W_fa, b_fa, alph_out, lens, xawe_h, t);
        // gates2 = xawe @ W_ihA^T   (M=64, N=2048)
        hipLaunchKernelGGL((gemm_k512<64, EPI_F32B, false>), dim3(16, 1), dim3(256), 0, stream,
                           (const void*)xawe_h, WihA_h, 2048, (const float*)nullptr, g2buf,
                           (f16*)nullptr, (const int*)nullptr);
        hipLaunchKernelGGL(k_cell, dim3(128), dim3(256), 0, stream,
                           g2buf, embIH + (size_t)t * 64 * 2048, Ybuf, cbuf,
                           hbuf_h + (size_t)t * 64 * 512);
    }

    // predictions = hbuf @ W_fc^T + b_fc, masked  (M=1280, N=30080 padded)
    hipLaunchKernelGGL((gemm_k512<128, EPI_PREDS, false>), dim3(CVP / 128, 10), dim3(256), 0, stream,
                       (const void*)hbuf_h, Wfc_h, CVP, b_fc, out, (f16*)nullptr, lens);
}